// Round 6
// baseline (160.188 us; speedup 1.0000x reference)
//
#include <hip/hip_runtime.h>
#include <hip/hip_bf16.h>
#include <math.h>

// Problem constants
#define NB      32
#define DDIM    256
#define HWSZ    1024                 // H*W
#define NTOK    32768                // NB*HWSZ
#define KCB     1024                 // codebook size
#define BSTRIDE (DDIM*HWSZ)          // floats per batch image

// ws layout (bytes)
#define OFF_ESQ  0                   // 1024 f32
#define OFF_SW   4096                // 1024*256 bf16, tile-swizzled (512 KB)
#define OFF_CNT  528384              // 1024 u32
#define OFF_DONE 532480              // 1 u32
#define OFF_MSUM 532488              // 1 double

typedef __attribute__((ext_vector_type(8))) short s8v;   // 8 bf16 (4 VGPR)
typedef __attribute__((ext_vector_type(4))) float f4v;   // MFMA acc

__device__ __forceinline__ unsigned short f2bf(float x) {
    __hip_bfloat16 h = __float2bfloat16(x);
    return __builtin_bit_cast(unsigned short, h);
}

typedef __attribute__((address_space(3))) unsigned       lds_u32;
typedef const __attribute__((address_space(1))) unsigned glob_u32;

__device__ __forceinline__ void glds16(const void* g, void* l) {
    __builtin_amdgcn_global_load_lds((glob_u32*)g, (lds_u32*)l, 16, 0, 0);
}

// ---------------------------------------------------------------- prep: esq + swizzled bf16 E + zero state
__global__ __launch_bounds__(256) void k_prep(const float* __restrict__ E,
                                              float* __restrict__ esq,
                                              unsigned short* __restrict__ Esw,
                                              unsigned* __restrict__ counts,
                                              unsigned* __restrict__ done,
                                              double* __restrict__ msum) {
    const int t = threadIdx.x;
    const int g = blockIdx.x * 256 + t;
    if (g < KCB) counts[g] = 0u;
    if (g == KCB)     *done = 0u;
    if (g == KCB + 1) *msum = 0.0;

    const int code = blockIdx.x * 8 + (t >> 5);
    const int l = t & 31, kc = l >> 3, p = l & 7;
    const int jsrc = p ^ (code & 7);                 // pre-swizzle source chunk
    const float* src = &E[(size_t)code * DDIM + kc * 64 + jsrc * 8];
    const float4 v0 = *reinterpret_cast<const float4*>(src);
    const float4 v1 = *reinterpret_cast<const float4*>(src + 4);

    double s = (double)v0.x * v0.x + (double)v0.y * v0.y +
               (double)v0.z * v0.z + (double)v0.w * v0.w +
               (double)v1.x * v1.x + (double)v1.y * v1.y +
               (double)v1.z * v1.z + (double)v1.w * v1.w;
#pragma unroll
    for (int off = 1; off < 32; off <<= 1) s += __shfl_xor(s, off, 64);
    if (l == 0) esq[code] = (float)s;

    unsigned q0 = (unsigned)f2bf(v0.x) | ((unsigned)f2bf(v0.y) << 16);
    unsigned q1 = (unsigned)f2bf(v0.z) | ((unsigned)f2bf(v0.w) << 16);
    unsigned q2 = (unsigned)f2bf(v1.x) | ((unsigned)f2bf(v1.y) << 16);
    unsigned q3 = (unsigned)f2bf(v1.z) | ((unsigned)f2bf(v1.w) << 16);
    uint4 pk = {q0, q1, q2, q3};
    size_t dst = (size_t)((code >> 7) * 4 + kc) * 8192 + (code & 127) * 64 + p * 8;
    *reinterpret_cast<uint4*>(&Esw[dst]) = pk;
}

// ---------------------------------------------------------------- fused main
// grid 512 x 256 thr (4 waves). Block: 64 tokens x all 1024 codes; 2 blocks/CU.
// Wave tile 64 tok x 32 codes (waves split N): a[4][8] full-K = 128 VGPR,
// acc[4][2]; B triple-buffered 16KB tiles via glds, counted vmcnt(4).
// Fused: argmin + histogram + Zq/loss epilogue + last-block finalize.
__global__ __launch_bounds__(256, 2) void k_main(const float* __restrict__ in,
                                                 const float* __restrict__ E,
                                                 const unsigned short* __restrict__ Esw,
                                                 const float* __restrict__ esq,
                                                 unsigned* __restrict__ counts,
                                                 unsigned* __restrict__ done,
                                                 double* __restrict__ msum,
                                                 float* __restrict__ out) {
    __shared__ __align__(16) unsigned short Bs[3][128 * 64];   // 48 KB
    __shared__ float    esq_lds[1024];                          // 4 KB
    __shared__ unsigned keyArr[4][64];
    __shared__ unsigned idx_lds[64];
    __shared__ double   sd[256];
    __shared__ int      lastflag;

    const int t = threadIdx.x;
    const int lane = t & 63, w = t >> 6;             // 4 waves
    const int lrow = lane & 15, lk = lane >> 4;
    const int n0 = blockIdx.x * 64;
    const int b = n0 >> 10, hw0 = n0 & 1023;
    const float* inb = in + (size_t)b * BSTRIDE + hw0;

    esq_lds[t]       = esq[t];
    esq_lds[t + 256] = esq[t + 256];
    esq_lds[t + 512] = esq[t + 512];
    esq_lds[t + 768] = esq[t + 768];

    // ---- A-stage: 4 phases through Bs[2]; full-K fragments -> 128 VGPR/thread
    s8v a[4][8];
    const int tok = t & 63, dsub = t >> 6;           // staging role: 16 d each
    for (int kc = 0; kc < 4; ++kc) {
        __syncthreads();                             // WAR on Bs[2]
        {
            float v[16];
#pragma unroll
            for (int j = 0; j < 16; ++j)
                v[j] = inb[(size_t)(kc * 64 + dsub * 16 + j) * HWSZ + tok];
#pragma unroll
            for (int h = 0; h < 2; ++h) {
                unsigned q0 = (unsigned)f2bf(v[h*8+0]) | ((unsigned)f2bf(v[h*8+1]) << 16);
                unsigned q1 = (unsigned)f2bf(v[h*8+2]) | ((unsigned)f2bf(v[h*8+3]) << 16);
                unsigned q2 = (unsigned)f2bf(v[h*8+4]) | ((unsigned)f2bf(v[h*8+5]) << 16);
                unsigned q3 = (unsigned)f2bf(v[h*8+6]) | ((unsigned)f2bf(v[h*8+7]) << 16);
                uint4 pk = {q0, q1, q2, q3};
                const int c = dsub * 2 + h;
                *reinterpret_cast<uint4*>(&Bs[2][tok * 64 + ((c ^ (tok & 7)) * 8)]) = pk;
            }
        }
        __syncthreads();
#pragma unroll
        for (int mi = 0; mi < 4; ++mi) {
            const int arow = mi * 16 + lrow;
#pragma unroll
            for (int ks = 0; ks < 2; ++ks)
                a[mi][kc * 2 + ks] = *reinterpret_cast<const s8v*>(
                    &Bs[2][arow * 64 + (((ks * 4 + lk) ^ (arow & 7)) * 8)]);
        }
    }

    // ---- prologue: issue tiles 0,1 (4 glds per wave per tile)
#pragma unroll
    for (int tp = 0; tp < 2; ++tp)
#pragma unroll
        for (int i = 0; i < 4; ++i)
            glds16(Esw + (size_t)tp * 8192 + (w * 4 + i) * 512 + lane * 8,
                   &Bs[tp][(w * 4 + i) * 512]);

    // ---- main loop: 8 code-tiles x 4 k-chunks, counted-vmcnt triple buffer
    unsigned best[16];
#pragma unroll
    for (int i = 0; i < 16; ++i) best[i] = 0xFFFFFFFFu;

    f4v acc[4][2];
    float es[2];

    for (int ss = 0; ss < 8; ++ss) {
#pragma unroll
        for (int kcs = 0; kcs < 4; ++kcs) {
            const int s = ss * 4 + kcs;
            // drain tile s only (tile s+1's 4 glds stay in flight)
            if (s < 31) asm volatile("s_waitcnt vmcnt(4)" ::: "memory");
            else        asm volatile("s_waitcnt vmcnt(0)" ::: "memory");
            __builtin_amdgcn_s_barrier();
            if (s + 2 < 32) {                        // prefetch tile s+2
                const unsigned short* sb = Esw + (size_t)(s + 2) * 8192;
                unsigned short* db = &Bs[(s + 2) % 3][0];
#pragma unroll
                for (int i = 0; i < 4; ++i)
                    glds16(sb + (w * 4 + i) * 512 + lane * 8, db + (w * 4 + i) * 512);
            }
            const unsigned short* bb = &Bs[s % 3][0];
            if (kcs == 0) {
#pragma unroll
                for (int ni = 0; ni < 2; ++ni) {
                    es[ni] = esq_lds[ss * 128 + w * 32 + ni * 16 + lrow];
#pragma unroll
                    for (int mi = 0; mi < 4; ++mi)
                        acc[mi][ni] = (f4v){0.f, 0.f, 0.f, 0.f};
                }
            }
#pragma unroll
            for (int ks = 0; ks < 2; ++ks) {
                s8v bfr[2];
#pragma unroll
                for (int ni = 0; ni < 2; ++ni) {
                    const int crow = w * 32 + ni * 16 + lrow;
                    bfr[ni] = *reinterpret_cast<const s8v*>(
                        &bb[crow * 64 + (((ks * 4 + lk) ^ (crow & 7)) * 8)]);
                }
#pragma unroll
                for (int mi = 0; mi < 4; ++mi)
#pragma unroll
                    for (int ni = 0; ni < 2; ++ni)
                        acc[mi][ni] = __builtin_amdgcn_mfma_f32_16x16x32_bf16(
                            a[mi][kcs * 2 + ks], bfr[ni], acc[mi][ni], 0, 0, 0);
            }
            if (kcs == 3) {                          // fold dist into 22-bit keys
#pragma unroll
                for (int mi = 0; mi < 4; ++mi)
#pragma unroll
                    for (int r = 0; r < 4; ++r) {
                        unsigned cur = best[mi * 4 + r];
#pragma unroll
                        for (int ni = 0; ni < 2; ++ni) {
                            float dv = fmaf(-2.0f, acc[mi][ni][r], es[ni]);
                            unsigned u = __float_as_uint(dv);
                            u = (u & 0x80000000u) ? ~u : (u | 0x80000000u);
                            unsigned key = (u & 0xFFFFFC00u)
                                         | (unsigned)(ss * 128 + w * 32 + ni * 16 + lrow);
                            cur = key < cur ? key : cur;
                        }
                        best[mi * 4 + r] = cur;
                    }
            }
        }
    }

    // ---- cross-lane argmin over lrow; token = mi*16 + lk*4 + r
#pragma unroll
    for (int mi = 0; mi < 4; ++mi)
#pragma unroll
        for (int r = 0; r < 4; ++r) {
            unsigned k = best[mi * 4 + r];
#pragma unroll
            for (int off = 1; off < 16; off <<= 1) {
                unsigned o = __shfl_xor(k, off, 64);
                k = o < k ? o : k;
            }
            if (lrow == 0) keyArr[w][mi * 16 + lk * 4 + r] = k;
        }
    __syncthreads();
    if (t < 64) {
        unsigned k0 = keyArr[0][t], k1 = keyArr[1][t];
        unsigned k2 = keyArr[2][t], k3 = keyArr[3][t];
        unsigned km = k0 < k1 ? k0 : k1;
        unsigned kn = k2 < k3 ? k2 : k3;
        idx_lds[t] = (km < kn ? km : kn) & 1023u;
    }
    __syncthreads();

    // ---- histogram (block-dedup: one atomic per distinct code)
    if (t < 64) {
        unsigned my = idx_lds[t];
        int cnt = 0; bool lead = true;
        for (int j = 0; j < 64; ++j) {
            unsigned v = idx_lds[j];
            if (v == my) { ++cnt; if (j < t) lead = false; }
        }
        if (lead) atomicAdd(&counts[my], (unsigned)cnt);
    }

    // ---- fused epilogue (vectorized): thread = 4 tokens x 16 d
    {
        const int tg = (t & 15) * 4;                 // tokens tg..tg+3
        const int dseg = t >> 4;                     // 16 d each
        unsigned id[4];
#pragma unroll
        for (int jj = 0; jj < 4; ++jj) id[jj] = idx_lds[tg + jj];
        const float* zbase = inb + tg;
        float* obase = out + 1 + (size_t)b * BSTRIDE + hw0 + tg;
        double sacc = 0.0;
#pragma unroll
        for (int q = 0; q < 4; ++q) {
            const int d0 = dseg * 16 + q * 4;
            float zz[4][4], ee[4][4];                // [d][token] / [token][d]
#pragma unroll
            for (int dd = 0; dd < 4; ++dd) {
                float4 z = *reinterpret_cast<const float4*>(zbase + (size_t)(d0 + dd) * HWSZ);
                zz[dd][0] = z.x; zz[dd][1] = z.y; zz[dd][2] = z.z; zz[dd][3] = z.w;
            }
#pragma unroll
            for (int jj = 0; jj < 4; ++jj) {
                float4 e = *reinterpret_cast<const float4*>(E + (size_t)id[jj] * DDIM + d0);
                ee[jj][0] = e.x; ee[jj][1] = e.y; ee[jj][2] = e.z; ee[jj][3] = e.w;
            }
#pragma unroll
            for (int dd = 0; dd < 4; ++dd) {
                float4 o;
                float df0 = __fsub_rn(ee[0][dd], zz[dd][0]);
                float df1 = __fsub_rn(ee[1][dd], zz[dd][1]);
                float df2 = __fsub_rn(ee[2][dd], zz[dd][2]);
                float df3 = __fsub_rn(ee[3][dd], zz[dd][3]);
                o.x = __fadd_rn(zz[dd][0], df0);
                o.y = __fadd_rn(zz[dd][1], df1);
                o.z = __fadd_rn(zz[dd][2], df2);
                o.w = __fadd_rn(zz[dd][3], df3);
                *reinterpret_cast<float4*>(obase + (size_t)(d0 + dd) * HWSZ) = o;
                sacc += (double)__fmul_rn(df0, df0) + (double)__fmul_rn(df1, df1)
                      + (double)__fmul_rn(df2, df2) + (double)__fmul_rn(df3, df3);
            }
        }
        sd[t] = sacc;
    }
    __syncthreads();
    for (int off = 128; off; off >>= 1) {
        if (t < off) sd[t] += sd[t + off];
        __syncthreads();
    }

    // ---- last-block finalize (device-scope)
    if (t == 0) {
        atomicAdd(msum, sd[0]);                      // f64, device scope
        __threadfence();
        unsigned old = __hip_atomic_fetch_add(done, 1u, __ATOMIC_ACQ_REL,
                                              __HIP_MEMORY_SCOPE_AGENT);
        lastflag = (old == 511u);
    }
    __syncthreads();
    if (lastflag) {
        __threadfence();
        double es_ = 0.0;
#pragma unroll
        for (int j = 0; j < 4; ++j) {
            unsigned c = __hip_atomic_load(&counts[t * 4 + j], __ATOMIC_RELAXED,
                                           __HIP_MEMORY_SCOPE_AGENT);
            float p = (float)c / 32768.0f;           // exact (div by 2^15)
            es_ += (double)__fmul_rn(p, log2f(__fadd_rn(p, 1e-10f)));
        }
        sd[t] = es_;
        __syncthreads();
        for (int off = 128; off; off >>= 1) {
            if (t < off) sd[t] += sd[t + off];
            __syncthreads();
        }
        if (t == 0) {
            double msv = __hip_atomic_load(msum, __ATOMIC_RELAXED,
                                           __HIP_MEMORY_SCOPE_AGENT);
            float e = (float)(msv / 8388608.0);      // mean over B*D*H*W
            float q = e;                             // numerically identical in ref
            float loss = __fadd_rn(q, __fmul_rn(0.25f, e));
            float ent = -(float)sd[0];
            float words = exp2f(ent);
            out[0] = loss;
            out[1 + 8388608 + 0] = e;
            out[1 + 8388608 + 1] = q;
            out[1 + 8388608 + 2] = words;
        }
    }
}

// ---------------------------------------------------------------- launch
extern "C" void kernel_launch(void* const* d_in, const int* in_sizes, int n_in,
                              void* d_out, int out_size, void* d_ws, size_t ws_size,
                              hipStream_t stream) {
    const float* in = (const float*)d_in[0];
    const float* E  = (const float*)d_in[1];
    float* out = (float*)d_out;
    char* ws = (char*)d_ws;
    float*          esq    = (float*)(ws + OFF_ESQ);
    unsigned short* Esw    = (unsigned short*)(ws + OFF_SW);
    unsigned*       counts = (unsigned*)(ws + OFF_CNT);
    unsigned*       done   = (unsigned*)(ws + OFF_DONE);
    double*         msum   = (double*)(ws + OFF_MSUM);

    hipLaunchKernelGGL(k_prep, dim3(128), dim3(256), 0, stream,
                       E, esq, Esw, counts, done, msum);
    hipLaunchKernelGGL(k_main, dim3(512), dim3(256), 0, stream,
                       in, E, Esw, esq, counts, done, msum, out);
}